// Round 11
// baseline (441.487 us; speedup 1.0000x reference)
//
#include <hip/hip_runtime.h>
#include <hip/hip_bf16.h>

// LSTM B=1024,T=512,F=64,H=128. R10 skeleton (318us best): 256 blocks x 4
// rows, 8 waves, 1 block/CU, weights persistent in regs (96 VGPR), A-row
// rotation (D reg0 = own batch row), x loads+pack+x-MFMAs at r==0, two
// 2-deep h-MFMA chains, lgkm-only barriers, exp2 pre-scaled weights,
// h_sm dbuf HPAD=144. Lessons: launch_bounds>2 spills (R5); 2-block/CU
// serializes (R7); depth-1 MFMA fan-out stalls (R8); chunk-tail x-work
// wrecks schedule (R9). Calibration (R10): step 1491cyc = 640 MFMA issue +
// ~610 VALU issue + ~240 exposed -> issue-bound; only VALU trims left.
// R11 trims: (1) tc-unroll x2 ping-pong xg/xld (no rotate movs);
// (2) persistent bias4 splat vectors; (3) pre-scaled cell state
// cs=2log2e*c with g2=2log2e*tanh(.) -> c->h chain loses a mul.

#define T_SEQ   512
#define F_IN    64
#define H_DIM   128
#define BB      4
#define NTHREADS 512
#define NG      4    // gate tiles per wave
#define KH      4    // h k-steps (K=128)
#define CH      4    // timestep chunk for batched x-GEMM
#define HPAD    144

typedef __bf16 bf16x8 __attribute__((ext_vector_type(8)));
typedef float  floatx4 __attribute__((ext_vector_type(4)));

#define L2E 1.44269504f

__device__ __forceinline__ unsigned pk2_bf16(float a, float b) {
    unsigned ua = __builtin_bit_cast(unsigned, a);
    unsigned ub = __builtin_bit_cast(unsigned, b);
    return ((ua + 0x8000u) >> 16) | ((ub + 0x8000u) & 0xFFFF0000u);
}
__device__ __forceinline__ bf16x8 pack_frag(const float4 lo, const float4 hi) {
    union { unsigned u[4]; bf16x8 v; } r;
    r.u[0] = pk2_bf16(lo.x, lo.y);
    r.u[1] = pk2_bf16(lo.z, lo.w);
    r.u[2] = pk2_bf16(hi.x, hi.y);
    r.u[3] = pk2_bf16(hi.z, hi.w);
    return r.v;
}
__device__ __forceinline__ __bf16 bf16_rhu(float f) {
    unsigned u = __builtin_bit_cast(unsigned, f) + 0x8000u;
    unsigned short s = (unsigned short)(u >> 16);
    return __builtin_bit_cast(__bf16, s);
}
__device__ __forceinline__ __bf16 to_bf16(float f) {   // RNE, prologue only
    union { __hip_bfloat16 h; __bf16 b; } u;
    u.h = __float2bfloat16(f);
    return u.b;
}
__device__ __forceinline__ float fast_rcp(float x) { return __builtin_amdgcn_rcpf(x); }
__device__ __forceinline__ float exp2_f(float x) { return __builtin_amdgcn_exp2f(x); }
// gate inputs PRE-SCALED: sigmoid by log2e, tanh by 2*log2e
__device__ __forceinline__ float sigmoid_s(float xs) {   // xs = x*log2e
    return fast_rcp(1.0f + exp2_f(-xs));
}
__device__ __forceinline__ float tanh_s(float xs) {      // xs = x*2log2e
    return __builtin_fmaf(-2.0f, fast_rcp(1.0f + exp2_f(xs)), 1.0f);
}
// 2log2e * tanh(x) with xs = x*2log2e — same op count as tanh_s
__device__ __forceinline__ float tanh2_s(float xs) {
    return __builtin_fmaf(-4.0f * L2E, fast_rcp(1.0f + exp2_f(xs)), 2.0f * L2E);
}
// barrier with LDS visibility but NO vmcnt drain (x prefetch stays in flight)
__device__ __forceinline__ void lds_barrier() {
    asm volatile("s_waitcnt lgkmcnt(0)\n\ts_barrier" ::: "memory");
}

__global__ __launch_bounds__(NTHREADS, 2)
void lstm_fused_kernel(const float* __restrict__ x,
                       const float* __restrict__ W_ih,
                       const float* __restrict__ W_hh,
                       const float* __restrict__ b_ih,
                       const float* __restrict__ b_hh,
                       const float* __restrict__ W_out,
                       const float* __restrict__ b_out,
                       float* __restrict__ out)
{
    const int tid = threadIdx.x;
    const int w   = tid >> 6;
    const int l   = tid & 63;
    const int lm  = l & 15;        // A row within tile; B col-within-tile
    const int q   = l >> 4;        // quad: A k-sub; D row group; EW batch row
    const int b0  = blockIdx.x * BB;
    const int jcol = w * 16 + lm;  // hidden col this lane EWs (batch row q)
    const int rot  = (lm + (lm >> 2)) & 3;  // A-row rotation: D reg0 = own row

    __shared__ __align__(16) __bf16 h_sm[2][BB][HPAD];
    __shared__ float hf_sm[BB][H_DIM];

    // persistent weight B-frags, PRE-SCALED (i,f,o x log2e; g x 2log2e):
    // elem j = Wsc[n][kb+j], n = g*128 + jcol, kb = s*32 + q*8;
    // s<4 -> W_hh, s>=4 -> W_ih(k-128). Persistent scaled bias4 per gate.
    bf16x8 wf[NG][KH + 2];
    floatx4 bias4[NG];
    #pragma unroll
    for (int g = 0; g < NG; ++g) {
        const float sc = (g == 2) ? (2.0f * L2E) : L2E;
        const int n = g * H_DIM + jcol;
        const float bsc = (b_ih[n] + b_hh[n]) * sc;
        bias4[g] = floatx4{bsc, bsc, bsc, bsc};
        #pragma unroll
        for (int s = 0; s < KH + 2; ++s) {
            const int kb = s * 32 + q * 8;
            const float* src = (kb < 128) ? (W_hh + (size_t)n * 128 + kb)
                                          : (W_ih + (size_t)n * 64 + (kb - 128));
            const float4 f0 = *reinterpret_cast<const float4*>(src);
            const float4 f1 = *reinterpret_cast<const float4*>(src + 4);
            bf16x8 v;
            v[0] = to_bf16(f0.x * sc); v[1] = to_bf16(f0.y * sc);
            v[2] = to_bf16(f0.z * sc); v[3] = to_bf16(f0.w * sc);
            v[4] = to_bf16(f1.x * sc); v[5] = to_bf16(f1.y * sc);
            v[6] = to_bf16(f1.z * sc); v[7] = to_bf16(f1.w * sc);
            wf[g][s] = v;
        }
    }

    for (int idx = tid; idx < 2 * BB * HPAD; idx += NTHREADS)
        (&h_sm[0][0][0])[idx] = to_bf16(0.0f);

    // x-GEMM A source: A row m: br = m>>2, tsub = m&3 -> lane q reg r =
    // xg[row q][tc+r] (matches EW row q, no select)
    const float* xga = x + ((size_t)(b0 + (lm >> 2)) * T_SEQ + (lm & 3)) * F_IN + q * 8;

    // ping-pong buffers: even chunk consumes xg0 / packs xld1 / fills xld0;
    // odd chunk consumes xg1 / packs xld0 / fills xld1. No rotate movs.
    floatx4 xg0[NG], xg1[NG];
    float4  xld0[4], xld1[4];
    {
        const float4 a0 = *reinterpret_cast<const float4*>(xga);
        const float4 a1 = *reinterpret_cast<const float4*>(xga + 4);
        const float4 a2 = *reinterpret_cast<const float4*>(xga + 32);
        const float4 a3 = *reinterpret_cast<const float4*>(xga + 36);
        const bf16x8 ax0 = pack_frag(a0, a1);
        const bf16x8 ax1 = pack_frag(a2, a3);
        #pragma unroll
        for (int g = 0; g < NG; ++g) {
            xg0[g] = __builtin_amdgcn_mfma_f32_16x16x32_bf16(ax0, wf[g][KH + 0], bias4[g], 0, 0, 0);
            xg0[g] = __builtin_amdgcn_mfma_f32_16x16x32_bf16(ax1, wf[g][KH + 1], xg0[g], 0, 0, 0);
        }
        const float* xp = xga + CH * F_IN;
        xld1[0] = *reinterpret_cast<const float4*>(xp);
        xld1[1] = *reinterpret_cast<const float4*>(xp + 4);
        xld1[2] = *reinterpret_cast<const float4*>(xp + 32);
        xld1[3] = *reinterpret_cast<const float4*>(xp + 36);
    }

    float cs = 0.0f, hval = 0.0f;   // cs = 2log2e * c (pre-scaled cell state)
    const floatx4 zero4 = {0.f, 0.f, 0.f, 0.f};

    // one chunk of CH steps: consume xg_use; at r==0 pack xld_pack -> xg_fill
    // and issue loads for chunk tc/CH+2 into xld_fill
    auto chunk_body = [&](int tc, floatx4* xg_use, floatx4* xg_fill,
                          float4* xld_pack, float4* xld_fill) {
        #pragma unroll
        for (int r = 0; r < CH; ++r) {
            lds_barrier();   // h(tc+r-1) visible; x loads NOT drained

            if (r == 0) {
                const int tn = (tc + 2 * CH < T_SEQ) ? (tc + 2 * CH) : (T_SEQ - CH);
                const float* xp = xga + (size_t)tn * F_IN;
                xld_fill[0] = *reinterpret_cast<const float4*>(xp);
                xld_fill[1] = *reinterpret_cast<const float4*>(xp + 4);
                xld_fill[2] = *reinterpret_cast<const float4*>(xp + 32);
                xld_fill[3] = *reinterpret_cast<const float4*>(xp + 36);
                const bf16x8 ax0 = pack_frag(xld_pack[0], xld_pack[1]);
                const bf16x8 ax1 = pack_frag(xld_pack[2], xld_pack[3]);
                #pragma unroll
                for (int g = 0; g < NG; ++g) {
                    xg_fill[g] = __builtin_amdgcn_mfma_f32_16x16x32_bf16(ax0, wf[g][KH + 0], bias4[g], 0, 0, 0);
                    xg_fill[g] = __builtin_amdgcn_mfma_f32_16x16x32_bf16(ax1, wf[g][KH + 1], xg_fill[g], 0, 0, 0);
                }
            }

            // h-GEMM: A rows rotated -> D reg0 = own batch row q.
            // Two independent 2-deep MFMA chains.
            const int p = r & 1;   // CH even -> global parity == r&1
            const __bf16* hrow = &h_sm[p][rot][q * 8];
            bf16x8 ah[KH];
            #pragma unroll
            for (int s = 0; s < KH; ++s)
                ah[s] = *reinterpret_cast<const bf16x8*>(hrow + s * 32);
            floatx4 hacc0[NG], hacc1[NG];
            #pragma unroll
            for (int g = 0; g < NG; ++g) {
                hacc0[g] = __builtin_amdgcn_mfma_f32_16x16x32_bf16(ah[0], wf[g][0], zero4, 0, 0, 0);
                hacc1[g] = __builtin_amdgcn_mfma_f32_16x16x32_bf16(ah[2], wf[g][2], zero4, 0, 0, 0);
            }
            #pragma unroll
            for (int g = 0; g < NG; ++g) {
                hacc0[g] = __builtin_amdgcn_mfma_f32_16x16x32_bf16(ah[1], wf[g][1], hacc0[g], 0, 0, 0);
                hacc1[g] = __builtin_amdgcn_mfma_f32_16x16x32_bf16(ah[3], wf[g][3], hacc1[g], 0, 0, 0);
            }

            // gates pre-scaled; EW for (row q, col jcol), cs-domain cell state
            const float i_ = sigmoid_s(hacc0[0][0] + hacc1[0][0] + xg_use[0][r]);
            const float f_ = sigmoid_s(hacc0[1][0] + hacc1[1][0] + xg_use[1][r]);
            const float g2 = tanh2_s (hacc0[2][0] + hacc1[2][0] + xg_use[2][r]);
            const float o_ = sigmoid_s(hacc0[3][0] + hacc1[3][0] + xg_use[3][r]);
            cs   = __builtin_fmaf(f_, cs, i_ * g2);   // cs = 2log2e * c
            hval = o_ * tanh_s(cs);
            h_sm[p ^ 1][q][jcol] = bf16_rhu(hval);
        }
    };

    #pragma unroll 1
    for (int tc = 0; tc < T_SEQ; tc += 2 * CH) {
        chunk_body(tc,      xg0, xg1, xld1, xld0);
        chunk_body(tc + CH, xg1, xg0, xld0, xld1);
    }

    // projection: out[b] = h_T @ W_out^T + b_out
    hf_sm[q][jcol] = hval;
    __syncthreads();
    {
        const int m = tid >> 7, n = tid & 127;
        float sum = b_out[n];
        const float* wrow = W_out + (size_t)n * H_DIM;
        #pragma unroll 8
        for (int jj = 0; jj < H_DIM; ++jj)
            sum += hf_sm[m][jj] * wrow[jj];
        out[(size_t)(b0 + m) * H_DIM + n] = sum;
    }
}

extern "C" void kernel_launch(void* const* d_in, const int* in_sizes, int n_in,
                              void* d_out, int out_size, void* d_ws, size_t ws_size,
                              hipStream_t stream) {
    const float* x     = (const float*)d_in[0];
    const float* W_ih  = (const float*)d_in[1];
    const float* W_hh  = (const float*)d_in[2];
    const float* b_ih  = (const float*)d_in[3];
    const float* b_hh  = (const float*)d_in[4];
    const float* W_out = (const float*)d_in[5];
    const float* b_out = (const float*)d_in[6];
    float* out = (float*)d_out;

    lstm_fused_kernel<<<dim3(1024 / BB), dim3(NTHREADS), 0, stream>>>(
        x, W_ih, W_hh, b_ih, b_hh, W_out, b_out, out);
}

// Round 12
// 407.670 us; speedup vs baseline: 1.0830x; 1.0830x over previous
//
#include <hip/hip_runtime.h>
#include <hip/hip_bf16.h>

// LSTM B=1024,T=512,F=64,H=128. EXACT R10 skeleton (318us best): 256 blocks
// x 4 rows, 8 waves, 1 block/CU, weights persistent in regs (96 VGPR), A-row
// rotation (D reg0 = own batch row), x loads+pack+x-MFMAs at r==0, two
// 2-deep h-MFMA chains, lgkm-only barriers, exp2 pre-scaled weights, h_sm
// dbuf HPAD=144, single non-unrolled chunk loop WITH rotate movs (R11 proved
// the x2-unroll/ping-pong variant regresses: -60cyc VALU, +130cyc stall).
// Lessons: launch_bounds>2 spills (R5); 2-block/CU serializes (R7); depth-1
// MFMA fan-out stalls (R8); chunk-tail x-work wrecks schedule (R9); body
// restructuring loses schedule quality (R11).
// R12 = R10 + ONE serial-chain trim: cs-domain cell state (cs = 2log2e*c,
// g2 = 2log2e*tanh via same-cost fma form) -> c->h chain loses one v_mul.

#define T_SEQ   512
#define F_IN    64
#define H_DIM   128
#define BB      4
#define NTHREADS 512
#define NG      4    // gate tiles per wave
#define KH      4    // h k-steps (K=128)
#define CH      4    // timestep chunk for batched x-GEMM
#define HPAD    144

typedef __bf16 bf16x8 __attribute__((ext_vector_type(8)));
typedef float  floatx4 __attribute__((ext_vector_type(4)));

#define L2E 1.44269504f

__device__ __forceinline__ unsigned pk2_bf16(float a, float b) {
    unsigned ua = __builtin_bit_cast(unsigned, a);
    unsigned ub = __builtin_bit_cast(unsigned, b);
    return ((ua + 0x8000u) >> 16) | ((ub + 0x8000u) & 0xFFFF0000u);
}
__device__ __forceinline__ bf16x8 pack_frag(const float4 lo, const float4 hi) {
    union { unsigned u[4]; bf16x8 v; } r;
    r.u[0] = pk2_bf16(lo.x, lo.y);
    r.u[1] = pk2_bf16(lo.z, lo.w);
    r.u[2] = pk2_bf16(hi.x, hi.y);
    r.u[3] = pk2_bf16(hi.z, hi.w);
    return r.v;
}
__device__ __forceinline__ __bf16 bf16_rhu(float f) {
    unsigned u = __builtin_bit_cast(unsigned, f) + 0x8000u;
    unsigned short s = (unsigned short)(u >> 16);
    return __builtin_bit_cast(__bf16, s);
}
__device__ __forceinline__ __bf16 to_bf16(float f) {   // RNE, prologue only
    union { __hip_bfloat16 h; __bf16 b; } u;
    u.h = __float2bfloat16(f);
    return u.b;
}
__device__ __forceinline__ float fast_rcp(float x) { return __builtin_amdgcn_rcpf(x); }
__device__ __forceinline__ float exp2_f(float x) { return __builtin_amdgcn_exp2f(x); }
// gate inputs PRE-SCALED: sigmoid by log2e, tanh by 2*log2e
__device__ __forceinline__ float sigmoid_s(float xs) {   // xs = x*log2e
    return fast_rcp(1.0f + exp2_f(-xs));
}
__device__ __forceinline__ float tanh_s(float xs) {      // xs = x*2log2e
    return __builtin_fmaf(-2.0f, fast_rcp(1.0f + exp2_f(xs)), 1.0f);
}
// 2log2e * tanh(x) with xs = x*2log2e — same op count as tanh_s
__device__ __forceinline__ float tanh2_s(float xs) {
    return __builtin_fmaf(-4.0f * L2E, fast_rcp(1.0f + exp2_f(xs)), 2.0f * L2E);
}
// barrier with LDS visibility but NO vmcnt drain (x prefetch stays in flight)
__device__ __forceinline__ void lds_barrier() {
    asm volatile("s_waitcnt lgkmcnt(0)\n\ts_barrier" ::: "memory");
}

__global__ __launch_bounds__(NTHREADS, 2)
void lstm_fused_kernel(const float* __restrict__ x,
                       const float* __restrict__ W_ih,
                       const float* __restrict__ W_hh,
                       const float* __restrict__ b_ih,
                       const float* __restrict__ b_hh,
                       const float* __restrict__ W_out,
                       const float* __restrict__ b_out,
                       float* __restrict__ out)
{
    const int tid = threadIdx.x;
    const int w   = tid >> 6;
    const int l   = tid & 63;
    const int lm  = l & 15;        // A row within tile; B col-within-tile
    const int q   = l >> 4;        // quad: A k-sub; D row group; EW batch row
    const int b0  = blockIdx.x * BB;
    const int jcol = w * 16 + lm;  // hidden col this lane EWs (batch row q)
    const int rot  = (lm + (lm >> 2)) & 3;  // A-row rotation: D reg0 = own row

    __shared__ __align__(16) __bf16 h_sm[2][BB][HPAD];
    __shared__ float hf_sm[BB][H_DIM];

    // persistent weight B-frags, PRE-SCALED (i,f,o x log2e; g x 2log2e):
    // elem j = Wsc[n][kb+j], n = g*128 + jcol, kb = s*32 + q*8;
    // s<4 -> W_hh, s>=4 -> W_ih(k-128). Scaled bias per gate.
    bf16x8 wf[NG][KH + 2];
    float  biasf[NG];
    #pragma unroll
    for (int g = 0; g < NG; ++g) {
        const float sc = (g == 2) ? (2.0f * L2E) : L2E;
        const int n = g * H_DIM + jcol;
        biasf[g] = (b_ih[n] + b_hh[n]) * sc;
        #pragma unroll
        for (int s = 0; s < KH + 2; ++s) {
            const int kb = s * 32 + q * 8;
            const float* src = (kb < 128) ? (W_hh + (size_t)n * 128 + kb)
                                          : (W_ih + (size_t)n * 64 + (kb - 128));
            const float4 f0 = *reinterpret_cast<const float4*>(src);
            const float4 f1 = *reinterpret_cast<const float4*>(src + 4);
            bf16x8 v;
            v[0] = to_bf16(f0.x * sc); v[1] = to_bf16(f0.y * sc);
            v[2] = to_bf16(f0.z * sc); v[3] = to_bf16(f0.w * sc);
            v[4] = to_bf16(f1.x * sc); v[5] = to_bf16(f1.y * sc);
            v[6] = to_bf16(f1.z * sc); v[7] = to_bf16(f1.w * sc);
            wf[g][s] = v;
        }
    }

    for (int idx = tid; idx < 2 * BB * HPAD; idx += NTHREADS)
        (&h_sm[0][0][0])[idx] = to_bf16(0.0f);

    // x-GEMM A source: A row m: br = m>>2, tsub = m&3 -> lane q reg r =
    // xg[row q][tc+r] (matches EW row q, no select)
    const float* xga = x + ((size_t)(b0 + (lm >> 2)) * T_SEQ + (lm & 3)) * F_IN + q * 8;

    // prologue: xg_cur = bias + xg(chunk 0); xld = x(chunk 1)
    floatx4 xg_cur[NG];
    {
        const float4 a0 = *reinterpret_cast<const float4*>(xga);
        const float4 a1 = *reinterpret_cast<const float4*>(xga + 4);
        const float4 a2 = *reinterpret_cast<const float4*>(xga + 32);
        const float4 a3 = *reinterpret_cast<const float4*>(xga + 36);
        const bf16x8 ax0 = pack_frag(a0, a1);
        const bf16x8 ax1 = pack_frag(a2, a3);
        #pragma unroll
        for (int g = 0; g < NG; ++g) {
            const floatx4 bias4 = {biasf[g], biasf[g], biasf[g], biasf[g]};
            xg_cur[g] = __builtin_amdgcn_mfma_f32_16x16x32_bf16(ax0, wf[g][KH + 0], bias4, 0, 0, 0);
            xg_cur[g] = __builtin_amdgcn_mfma_f32_16x16x32_bf16(ax1, wf[g][KH + 1], xg_cur[g], 0, 0, 0);
        }
    }
    float4 xld[4];
    {
        const float* xp = xga + CH * F_IN;
        xld[0] = *reinterpret_cast<const float4*>(xp);
        xld[1] = *reinterpret_cast<const float4*>(xp + 4);
        xld[2] = *reinterpret_cast<const float4*>(xp + 32);
        xld[3] = *reinterpret_cast<const float4*>(xp + 36);
    }

    float cs = 0.0f, hval = 0.0f;   // cs = 2log2e * c (pre-scaled cell state)
    const floatx4 zero4 = {0.f, 0.f, 0.f, 0.f};

    #pragma unroll 1
    for (int tc = 0; tc < T_SEQ; tc += CH) {
        floatx4 xg_next[NG];
        float4  xnew[4];
        #pragma unroll
        for (int r = 0; r < CH; ++r) {
            lds_barrier();   // h(tc+r-1) visible; x loads NOT drained

            if (r == 0) {
                // loads for chunk C+2 — consumed at next chunk's r==0 pack;
                // ~4 steps in flight (never drained by a barrier)
                const int tn = (tc + 2 * CH < T_SEQ) ? (tc + 2 * CH) : (T_SEQ - CH);
                const float* xp = xga + (size_t)tn * F_IN;
                xnew[0] = *reinterpret_cast<const float4*>(xp);
                xnew[1] = *reinterpret_cast<const float4*>(xp + 4);
                xnew[2] = *reinterpret_cast<const float4*>(xp + 32);
                xnew[3] = *reinterpret_cast<const float4*>(xp + 36);
                // xg_next = bias + xg(chunk C+1) from xld
                const bf16x8 ax0 = pack_frag(xld[0], xld[1]);
                const bf16x8 ax1 = pack_frag(xld[2], xld[3]);
                #pragma unroll
                for (int g = 0; g < NG; ++g) {
                    const floatx4 bias4 = {biasf[g], biasf[g], biasf[g], biasf[g]};
                    xg_next[g] = __builtin_amdgcn_mfma_f32_16x16x32_bf16(ax0, wf[g][KH + 0], bias4, 0, 0, 0);
                    xg_next[g] = __builtin_amdgcn_mfma_f32_16x16x32_bf16(ax1, wf[g][KH + 1], xg_next[g], 0, 0, 0);
                }
            }

            // h-GEMM: A rows rotated -> D reg0 = own batch row q.
            // Two independent 2-deep MFMA chains.
            const int p = r & 1;
            const __bf16* hrow = &h_sm[p][rot][q * 8];
            bf16x8 ah[KH];
            #pragma unroll
            for (int s = 0; s < KH; ++s)
                ah[s] = *reinterpret_cast<const bf16x8*>(hrow + s * 32);
            floatx4 hacc0[NG], hacc1[NG];
            #pragma unroll
            for (int g = 0; g < NG; ++g) {
                hacc0[g] = __builtin_amdgcn_mfma_f32_16x16x32_bf16(ah[0], wf[g][0], zero4, 0, 0, 0);
                hacc1[g] = __builtin_amdgcn_mfma_f32_16x16x32_bf16(ah[2], wf[g][2], zero4, 0, 0, 0);
            }
            #pragma unroll
            for (int g = 0; g < NG; ++g) {
                hacc0[g] = __builtin_amdgcn_mfma_f32_16x16x32_bf16(ah[1], wf[g][1], hacc0[g], 0, 0, 0);
                hacc1[g] = __builtin_amdgcn_mfma_f32_16x16x32_bf16(ah[3], wf[g][3], hacc1[g], 0, 0, 0);
            }

            // gates pre-scaled; EW for (row q, col jcol); cs-domain chain
            const float i_ = sigmoid_s(hacc0[0][0] + hacc1[0][0] + xg_cur[0][r]);
            const float f_ = sigmoid_s(hacc0[1][0] + hacc1[1][0] + xg_cur[1][r]);
            const float g2 = tanh2_s (hacc0[2][0] + hacc1[2][0] + xg_cur[2][r]);
            const float o_ = sigmoid_s(hacc0[3][0] + hacc1[3][0] + xg_cur[3][r]);
            cs   = __builtin_fmaf(f_, cs, i_ * g2);   // cs = 2log2e * c
            hval = o_ * tanh_s(cs);
            h_sm[p ^ 1][q][jcol] = bf16_rhu(hval);
        }
        #pragma unroll
        for (int g = 0; g < NG; ++g) xg_cur[g] = xg_next[g];
        #pragma unroll
        for (int i = 0; i < 4; ++i)  xld[i] = xnew[i];
    }

    // projection: out[b] = h_T @ W_out^T + b_out
    hf_sm[q][jcol] = hval;
    __syncthreads();
    {
        const int m = tid >> 7, n = tid & 127;
        float sum = b_out[n];
        const float* wrow = W_out + (size_t)n * H_DIM;
        #pragma unroll 8
        for (int jj = 0; jj < H_DIM; ++jj)
            sum += hf_sm[m][jj] * wrow[jj];
        out[(size_t)(b0 + m) * H_DIM + n] = sum;
    }
}

extern "C" void kernel_launch(void* const* d_in, const int* in_sizes, int n_in,
                              void* d_out, int out_size, void* d_ws, size_t ws_size,
                              hipStream_t stream) {
    const float* x     = (const float*)d_in[0];
    const float* W_ih  = (const float*)d_in[1];
    const float* W_hh  = (const float*)d_in[2];
    const float* b_ih  = (const float*)d_in[3];
    const float* b_hh  = (const float*)d_in[4];
    const float* W_out = (const float*)d_in[5];
    const float* b_out = (const float*)d_in[6];
    float* out = (float*)d_out;

    lstm_fused_kernel<<<dim3(1024 / BB), dim3(NTHREADS), 0, stream>>>(
        x, W_ih, W_hh, b_ih, b_hh, W_out, b_out, out);
}